// Round 2
// baseline (484.860 us; speedup 1.0000x reference)
//
#include <hip/hip_runtime.h>
#include <cstdint>
#include <cstddef>

typedef _Float16 f16;
typedef _Float16 f16x8 __attribute__((ext_vector_type(8)));
typedef _Float16 f16x4 __attribute__((ext_vector_type(4)));
typedef float f32x16 __attribute__((ext_vector_type(16)));
typedef float f32x4 __attribute__((ext_vector_type(4)));

static constexpr int NPTS = 262144;

// Repacked weight offsets (in halfs). Each "tile" is 512 halfs = 64 lanes x 8.
// Fragment layout per tile (kt, ct): value = W[k][ch], k = kt*16 + (l>>5)*8 + j,
// ch = ct*32 + (l&31). Tiles ordered [segment][kt][ct], contiguous.
static constexpr int OFF_W0    = 0;        // 4 kt x 8 ct
static constexpr int OFF_W1    = 16384;    // 16 x 8
static constexpr int OFF_W2    = 81920;
static constexpr int OFF_W3    = 147456;
static constexpr int OFF_W4    = 212992;
static constexpr int OFF_W5    = 278528;   // w5b (16x8) then w5a (4x8), contiguous = 20 slices
static constexpr int OFF_W6    = 360448;
static constexpr int OFF_W7    = 425984;
static constexpr int OFF_FEAT  = 491520;
static constexpr int OFF_VIEWS = 557056;   // viewsA (16x4) then viewsB (2x4) = 18 slices of 2048
static constexpr int OFF_RGB   = 593920;   // 8 x 1

struct Seg { const float* src; int k0, rv, fo, ct, t0; };
struct RepParams { Seg seg[13]; f16* rep; };

__global__ void repack_kernel(RepParams P) {
  int tile = blockIdx.x;
  int s = 0;
  #pragma unroll
  for (int i = 1; i < 13; ++i)
    if (tile >= P.seg[i].t0) s = i;
  const Seg sg = P.seg[s];
  int local = tile - sg.t0;
  int kt = local / sg.ct;
  int ct = local - kt * sg.ct;
  int l = threadIdx.x;
  int ch = ct * 32 + (l & 31);
  int kbase = kt * 16 + ((l >> 5) << 3);
  f16x8 v;
  #pragma unroll
  for (int j = 0; j < 8; ++j) {
    int k = kbase + j;
    float val = 0.f;
    if (k < sg.rv && ch < sg.fo) val = sg.src[(size_t)(sg.k0 + k) * sg.fo + ch];
    v[j] = (f16)val;
  }
  *(f16x8*)(P.rep + (size_t)tile * 512 + (size_t)l * 8) = v;
}

struct MainParams {
  const float* x;
  const float* b[8];
  const float* feat_b;
  const float* alpha_w;
  const float* alpha_b;
  const float* views_b;
  const float* rgb_b;
  const f16* rep;
  float* out;
};

// Activation LDS addressing: [pt][256] f16, 512 B rows, XOR swizzle to avoid
// 32-way bank conflicts on the stride-512 ds_read_b128 B-fragment reads.
__device__ __forceinline__ int act_off(int pt, int kbyte) {
  return pt * 512 + (kbyte ^ ((pt & 15) << 4));
}

// Standard 256-out layer. Wave tile = 128 ch x 64 pt. acc[c][p] holds the
// (ct = chhalf*4+c, pt-tile p) 32x32 MFMA tile, D[ch][pt].
// A-fragments come DIRECTLY from global (L2-resident repacked weights) into
// registers — no LDS staging, no per-K-step barriers. B from act LDS for
// kt < KTA, then from xb register frags (KTX of them).
template<int KTA, int KTX>
__device__ __forceinline__ void layer_std(
    const f16* repL, const float* bias, bool relu,
    f16* act, const f16x8* xb,
    int lane, int chhalf, int ptbase)
{
  const int l31 = lane & 31;
  const int ln5 = lane >> 5;
  const int chb = chhalf * 128;

  f32x16 acc[4][2];
  #pragma unroll
  for (int c = 0; c < 4; ++c) {
    #pragma unroll
    for (int g = 0; g < 4; ++g) {
      f32x4 bv = *(const f32x4*)(bias + chb + c * 32 + g * 8 + (ln5 << 2));
      #pragma unroll
      for (int q = 0; q < 4; ++q) {
        acc[c][0][g * 4 + q] = bv[q];
        acc[c][1][g * 4 + q] = bv[q];
      }
    }
  }

  __syncthreads();  // prev epilogue writes -> visible to our B reads

  #pragma unroll 4
  for (int kt = 0; kt < KTA; ++kt) {
    f16x8 a[4], bfr[2];
    #pragma unroll
    for (int c = 0; c < 4; ++c)
      a[c] = *(const f16x8*)(repL + (size_t)(kt * 8 + chhalf * 4 + c) * 512 + (size_t)lane * 8);
    #pragma unroll
    for (int p = 0; p < 2; ++p) {
      int pt = ptbase + p * 32 + l31;
      bfr[p] = *(const f16x8*)((const char*)act + act_off(pt, (kt * 16 + ln5 * 8) * 2));
    }
    #pragma unroll
    for (int c = 0; c < 4; ++c)
      #pragma unroll
      for (int p = 0; p < 2; ++p)
        acc[c][p] = __builtin_amdgcn_mfma_f32_32x32x16_f16(a[c], bfr[p], acc[c][p], 0, 0, 0);
  }

  #pragma unroll
  for (int j = 0; j < KTX; ++j) {
    int kt = KTA + j;
    f16x8 a[4];
    #pragma unroll
    for (int c = 0; c < 4; ++c)
      a[c] = *(const f16x8*)(repL + (size_t)(kt * 8 + chhalf * 4 + c) * 512 + (size_t)lane * 8);
    #pragma unroll
    for (int c = 0; c < 4; ++c)
      #pragma unroll
      for (int p = 0; p < 2; ++p)
        acc[c][p] = __builtin_amdgcn_mfma_f32_32x32x16_f16(a[c], xb[p * KTX + j], acc[c][p], 0, 0, 0);
  }

  __syncthreads();  // all B reads done -> safe to overwrite act in place

  // Epilogue: C row = (r&3) + 8*(r>>2) + 4*(l>>5), col = l&31 (pt).
  #pragma unroll
  for (int c = 0; c < 4; ++c) {
    #pragma unroll
    for (int p = 0; p < 2; ++p) {
      int pt = ptbase + p * 32 + l31;
      #pragma unroll
      for (int g = 0; g < 4; ++g) {
        f16x4 h;
        #pragma unroll
        for (int q = 0; q < 4; ++q) {
          float v = acc[c][p][g * 4 + q];
          if (relu) v = fmaxf(v, 0.f);
          h[q] = (f16)v;
        }
        int ch = chb + c * 32 + g * 8 + (ln5 << 2);
        *(f16x4*)((char*)act + act_off(pt, ch * 2)) = h;
      }
    }
  }
}

// Views layer: in = feature(256 from act) + views(27 via reg frags), out = 128 ch, relu.
__device__ __forceinline__ void layer_views(
    const f16* repL, const float* bias, f16* act,
    const f16x8* vb, int lane, int chhalf, int ptbase)
{
  const int l31 = lane & 31;
  const int ln5 = lane >> 5;
  const int chb = chhalf * 64;

  f32x16 acc[2][2];
  #pragma unroll
  for (int c = 0; c < 2; ++c) {
    #pragma unroll
    for (int g = 0; g < 4; ++g) {
      f32x4 bv = *(const f32x4*)(bias + chb + c * 32 + g * 8 + (ln5 << 2));
      #pragma unroll
      for (int q = 0; q < 4; ++q) {
        acc[c][0][g * 4 + q] = bv[q];
        acc[c][1][g * 4 + q] = bv[q];
      }
    }
  }

  __syncthreads();

  #pragma unroll 4
  for (int kt = 0; kt < 16; ++kt) {
    f16x8 a[2], bfr[2];
    #pragma unroll
    for (int c = 0; c < 2; ++c)
      a[c] = *(const f16x8*)(repL + (size_t)(kt * 4 + chhalf * 2 + c) * 512 + (size_t)lane * 8);
    #pragma unroll
    for (int p = 0; p < 2; ++p) {
      int pt = ptbase + p * 32 + l31;
      bfr[p] = *(const f16x8*)((const char*)act + act_off(pt, (kt * 16 + ln5 * 8) * 2));
    }
    #pragma unroll
    for (int c = 0; c < 2; ++c)
      #pragma unroll
      for (int p = 0; p < 2; ++p)
        acc[c][p] = __builtin_amdgcn_mfma_f32_32x32x16_f16(a[c], bfr[p], acc[c][p], 0, 0, 0);
  }

  #pragma unroll
  for (int j = 0; j < 2; ++j) {
    int kt = 16 + j;
    f16x8 a[2];
    #pragma unroll
    for (int c = 0; c < 2; ++c)
      a[c] = *(const f16x8*)(repL + (size_t)(kt * 4 + chhalf * 2 + c) * 512 + (size_t)lane * 8);
    #pragma unroll
    for (int c = 0; c < 2; ++c)
      #pragma unroll
      for (int p = 0; p < 2; ++p)
        acc[c][p] = __builtin_amdgcn_mfma_f32_32x32x16_f16(a[c], vb[p * 2 + j], acc[c][p], 0, 0, 0);
  }

  __syncthreads();

  #pragma unroll
  for (int c = 0; c < 2; ++c) {
    #pragma unroll
    for (int p = 0; p < 2; ++p) {
      int pt = ptbase + p * 32 + l31;
      #pragma unroll
      for (int g = 0; g < 4; ++g) {
        f16x4 h;
        #pragma unroll
        for (int q = 0; q < 4; ++q) {
          float v = fmaxf(acc[c][p][g * 4 + q], 0.f);
          h[q] = (f16)v;
        }
        int ch = chb + c * 32 + g * 8 + (ln5 << 2);
        *(f16x4*)((char*)act + act_off(pt, ch * 2)) = h;
      }
    }
  }
}

// alpha = y . alpha_w + alpha_b (y still in act). 2 threads per point.
__device__ __forceinline__ void alpha_pass(const f16* act, const float* aw,
                                           const float* ab, float* alds, int tid)
{
  __syncthreads();
  int pt = tid >> 1;
  int h = tid & 1;
  float s = 0.f;
  #pragma unroll
  for (int i = 0; i < 16; ++i) {
    int k0 = h * 128 + i * 8;
    f16x8 v = *(const f16x8*)((const char*)act + act_off(pt, k0 * 2));
    f32x4 wa = *(const f32x4*)(aw + k0);
    f32x4 wb = *(const f32x4*)(aw + k0 + 4);
    #pragma unroll
    for (int q = 0; q < 4; ++q) {
      s += (float)v[q] * wa[q];
      s += (float)v[q + 4] * wb[q];
    }
  }
  s += __shfl_xor(s, 1);
  if (h == 0) alds[pt] = s + ab[0];
}

// rgb (128 -> 3 via one padded 32-ch MFMA tile per 32-pt wave tile) + packed store.
__device__ __forceinline__ void layer_rgb_store(
    const f16* repL, f16* act, const float* alds,
    const float* rgb_b, float* out, int pt0, int lane, int wid)
{
  f32x16 acc = {};
  const int ptb = wid * 32;
  __syncthreads();
  #pragma unroll
  for (int kt = 0; kt < 8; ++kt) {
    f16x8 a = *(const f16x8*)(repL + (size_t)kt * 512 + (size_t)lane * 8);
    int pt = ptb + (lane & 31);
    f16x8 b = *(const f16x8*)((const char*)act + act_off(pt, (kt * 16 + (lane >> 5) * 8) * 2));
    acc = __builtin_amdgcn_mfma_f32_32x32x16_f16(a, b, acc, 0, 0, 0);
  }
  if (lane < 32) {
    int pt = ptb + lane;
    float4 o;
    o.x = acc[0] + rgb_b[0];
    o.y = acc[1] + rgb_b[1];
    o.z = acc[2] + rgb_b[2];
    o.w = alds[pt];
    *(float4*)(out + (size_t)(pt0 + pt) * 4) = o;
  }
}

__device__ __forceinline__ void load_pos_frags(const float* x, int pt0, int ptbase,
                                               int lane, f16x8* pf)
{
  const int l31 = lane & 31, ln5 = lane >> 5;
  #pragma unroll
  for (int p = 0; p < 2; ++p) {
    const float* row = x + (size_t)(pt0 + ptbase + p * 32 + l31) * 90;
    #pragma unroll
    for (int kt = 0; kt < 4; ++kt) {
      f16x8 v;
      #pragma unroll
      for (int j = 0; j < 8; ++j) {
        int c = kt * 16 + ln5 * 8 + j;
        v[j] = (f16)((c < 63) ? row[c] : 0.f);
      }
      pf[p * 4 + kt] = v;
    }
  }
}

__device__ __forceinline__ void load_views_frags(const float* x, int pt0, int ptbase,
                                                 int lane, f16x8* vf)
{
  const int l31 = lane & 31, ln5 = lane >> 5;
  #pragma unroll
  for (int p = 0; p < 2; ++p) {
    const float* row = x + (size_t)(pt0 + ptbase + p * 32 + l31) * 90;
    #pragma unroll
    for (int kt = 0; kt < 2; ++kt) {
      f16x8 v;
      #pragma unroll
      for (int j = 0; j < 8; ++j) {
        int c = kt * 16 + ln5 * 8 + j;
        v[j] = (f16)((c < 27) ? row[63 + c] : 0.f);
      }
      vf[p * 2 + kt] = v;
    }
  }
}

__global__ __launch_bounds__(512, 2) void nerf_main(MainParams P) {
  __shared__ __align__(16) f16 act[65536];   // 128 KB: [256 pt][256 k], swizzled
  __shared__ float alds[256];

  const int tid = threadIdx.x;
  const int lane = tid & 63;
  const int wid = tid >> 6;
  const int chhalf = wid >> 2;           // 0/1 -> ch 0..127 / 128..255
  const int ptbase = (wid & 3) * 64;     // 64-pt quarter
  const int pt0 = blockIdx.x * 256;

  {
    f16x8 pf[8];
    load_pos_frags(P.x, pt0, ptbase, lane, pf);
    layer_std<0, 4>(P.rep + OFF_W0, P.b[0], true, act, pf, lane, chhalf, ptbase);
  }
  layer_std<16, 0>(P.rep + OFF_W1, P.b[1], true, act, nullptr, lane, chhalf, ptbase);
  layer_std<16, 0>(P.rep + OFF_W2, P.b[2], true, act, nullptr, lane, chhalf, ptbase);
  layer_std<16, 0>(P.rep + OFF_W3, P.b[3], true, act, nullptr, lane, chhalf, ptbase);
  layer_std<16, 0>(P.rep + OFF_W4, P.b[4], true, act, nullptr, lane, chhalf, ptbase);
  {
    f16x8 pf[8];
    load_pos_frags(P.x, pt0, ptbase, lane, pf);
    layer_std<16, 4>(P.rep + OFF_W5, P.b[5], true, act, pf, lane, chhalf, ptbase);
  }
  layer_std<16, 0>(P.rep + OFF_W6, P.b[6], true, act, nullptr, lane, chhalf, ptbase);
  layer_std<16, 0>(P.rep + OFF_W7, P.b[7], true, act, nullptr, lane, chhalf, ptbase);

  alpha_pass(act, P.alpha_w, P.alpha_b, alds, tid);

  layer_std<16, 0>(P.rep + OFF_FEAT, P.feat_b, false, act, nullptr, lane, chhalf, ptbase);

  {
    f16x8 vf[4];
    load_views_frags(P.x, pt0, ptbase, lane, vf);
    layer_views(P.rep + OFF_VIEWS, P.views_b, act, vf, lane, chhalf, ptbase);
  }

  layer_rgb_store(P.rep + OFF_RGB, act, alds, P.rgb_b, P.out, pt0, lane, wid);

  // Second tuple output: zeros (N, 3)
  float* out2 = P.out + (size_t)NPTS * 4;
  if (tid < 384) {
    *(float2*)(out2 + (size_t)blockIdx.x * 768 + (size_t)tid * 2) = make_float2(0.f, 0.f);
  }
}

extern "C" void kernel_launch(void* const* d_in, const int* in_sizes, int n_in,
                              void* d_out, int out_size, void* d_ws, size_t ws_size,
                              hipStream_t stream) {
  (void)in_sizes; (void)n_in; (void)out_size; (void)ws_size;

  RepParams rp;
  rp.seg[0]  = { (const float*)d_in[1],    0,  63, 256, 8,    0 }; // w0 (pad K 63->64)
  rp.seg[1]  = { (const float*)d_in[3],    0, 256, 256, 8,   32 }; // w1
  rp.seg[2]  = { (const float*)d_in[5],    0, 256, 256, 8,  160 }; // w2
  rp.seg[3]  = { (const float*)d_in[7],    0, 256, 256, 8,  288 }; // w3
  rp.seg[4]  = { (const float*)d_in[9],    0, 256, 256, 8,  416 }; // w4
  rp.seg[5]  = { (const float*)d_in[11],  63, 256, 256, 8,  544 }; // w5 y-part (rows 63..318)
  rp.seg[6]  = { (const float*)d_in[11],   0,  63, 256, 8,  672 }; // w5 pos-part (rows 0..62)
  rp.seg[7]  = { (const float*)d_in[13],   0, 256, 256, 8,  704 }; // w6
  rp.seg[8]  = { (const float*)d_in[15],   0, 256, 256, 8,  832 }; // w7
  rp.seg[9]  = { (const float*)d_in[17],   0, 256, 256, 8,  960 }; // feat_w
  rp.seg[10] = { (const float*)d_in[21],   0, 256, 128, 4, 1088 }; // views_w feature-part
  rp.seg[11] = { (const float*)d_in[21], 256,  27, 128, 4, 1152 }; // views_w views-part
  rp.seg[12] = { (const float*)d_in[23],   0, 128,   3, 1, 1160 }; // rgb_w (pad 3->32 ch)
  rp.rep = (f16*)d_ws;
  repack_kernel<<<1168, 64, 0, stream>>>(rp);

  MainParams mp;
  mp.x = (const float*)d_in[0];
  for (int i = 0; i < 8; ++i) mp.b[i] = (const float*)d_in[2 + 2 * i];
  mp.feat_b  = (const float*)d_in[18];
  mp.alpha_w = (const float*)d_in[19];
  mp.alpha_b = (const float*)d_in[20];
  mp.views_b = (const float*)d_in[22];
  mp.rgb_b   = (const float*)d_in[24];
  mp.rep = (const f16*)d_ws;
  mp.out = (float*)d_out;
  nerf_main<<<1024, 512, 0, stream>>>(mp);
}

// Round 3
// 402.947 us; speedup vs baseline: 1.2033x; 1.2033x over previous
//
#include <hip/hip_runtime.h>
#include <cstdint>
#include <cstddef>

typedef _Float16 f16;
typedef _Float16 f16x8 __attribute__((ext_vector_type(8)));
typedef _Float16 f16x4 __attribute__((ext_vector_type(4)));
typedef float f32x16 __attribute__((ext_vector_type(16)));
typedef float f32x4 __attribute__((ext_vector_type(4)));

static constexpr int NPTS = 262144;

// Repacked weight offsets (in halfs). Each "tile" is 512 halfs = 64 lanes x 8.
// Fragment layout per tile (kt, ct): value = W[k][ch], k = kt*16 + (l>>5)*8 + j,
// ch = ct*32 + (l&31). Tiles ordered [segment][kt][ct], contiguous.
static constexpr int OFF_W0    = 0;        // 4 kt x 8 ct
static constexpr int OFF_W1    = 16384;    // 16 x 8
static constexpr int OFF_W2    = 81920;
static constexpr int OFF_W3    = 147456;
static constexpr int OFF_W4    = 212992;
static constexpr int OFF_W5    = 278528;   // w5b (16x8) then w5a (4x8), contiguous = 20 slices
static constexpr int OFF_W6    = 360448;
static constexpr int OFF_W7    = 425984;
static constexpr int OFF_FEAT  = 491520;
static constexpr int OFF_VIEWS = 557056;   // viewsA (16x4) then viewsB (2x4) = 18 slices of 2048
static constexpr int OFF_RGB   = 593920;   // 8 x 1

struct Seg { const float* src; int k0, rv, fo, ct, t0; };
struct RepParams { Seg seg[13]; f16* rep; };

__global__ void repack_kernel(RepParams P) {
  int tile = blockIdx.x;
  int s = 0;
  #pragma unroll
  for (int i = 1; i < 13; ++i)
    if (tile >= P.seg[i].t0) s = i;
  const Seg sg = P.seg[s];
  int local = tile - sg.t0;
  int kt = local / sg.ct;
  int ct = local - kt * sg.ct;
  int l = threadIdx.x;
  int ch = ct * 32 + (l & 31);
  int kbase = kt * 16 + ((l >> 5) << 3);
  f16x8 v;
  #pragma unroll
  for (int j = 0; j < 8; ++j) {
    int k = kbase + j;
    float val = 0.f;
    if (k < sg.rv && ch < sg.fo) val = sg.src[(size_t)(sg.k0 + k) * sg.fo + ch];
    v[j] = (f16)val;
  }
  *(f16x8*)(P.rep + (size_t)tile * 512 + (size_t)l * 8) = v;
}

struct MainParams {
  const float* x;
  const float* b[8];
  const float* feat_b;
  const float* alpha_w;
  const float* alpha_b;
  const float* views_b;
  const float* rgb_b;
  const f16* rep;
  float* out;
};

// Activation LDS addressing: [pt<64][256ch] f16, 512 B rows, XOR swizzle to
// avoid 32-way bank conflicts on the stride-512 ds_read_b128 B-fragment reads.
__device__ __forceinline__ int act_off(int pt, int kbyte) {
  return pt * 512 + (kbyte ^ ((pt & 15) << 4));
}

// Standard 256-out layer, 64-pt block, 4 waves. Wave w computes ch [64w,64w+64)
// x 64 pts: acc[c][p] = 32x32 tile (ct = 2w+c, p-tile p), D[ch][pt].
// A-frags straight from global (L2-resident repack) into registers.
// xb (KTX reg-fragments, e.g. skip-connection pos) are consumed FIRST so the
// registers die early (pressure: target <=128 unified regs/wave).
template<int KTA, int KTX>
__device__ __forceinline__ void layer_std64(
    const f16* repL, const float* bias, bool relu,
    f16* act, const f16x8* xb, int lane, int w)
{
  const int l31 = lane & 31;
  const int ln5 = lane >> 5;
  const int chb = w * 64;

  f32x16 acc[2][2];
  #pragma unroll
  for (int c = 0; c < 2; ++c) {
    #pragma unroll
    for (int g = 0; g < 4; ++g) {
      f32x4 bv = *(const f32x4*)(bias + chb + c * 32 + g * 8 + (ln5 << 2));
      #pragma unroll
      for (int q = 0; q < 4; ++q) {
        acc[c][0][g * 4 + q] = bv[q];
        acc[c][1][g * 4 + q] = bv[q];
      }
    }
  }

  // Skip-connection part first (kills xb registers early).
  #pragma unroll
  for (int j = 0; j < KTX; ++j) {
    int kt = KTA + j;
    f16x8 a[2];
    #pragma unroll
    for (int c = 0; c < 2; ++c)
      a[c] = *(const f16x8*)(repL + (size_t)(kt * 8 + 2 * w + c) * 512 + (size_t)lane * 8);
    #pragma unroll
    for (int c = 0; c < 2; ++c)
      #pragma unroll
      for (int p = 0; p < 2; ++p)
        acc[c][p] = __builtin_amdgcn_mfma_f32_32x32x16_f16(a[c], xb[p * KTX + j], acc[c][p], 0, 0, 0);
  }

  __syncthreads();  // prev epilogue writes -> visible to our B reads

  #pragma unroll 2
  for (int kt = 0; kt < KTA; ++kt) {
    f16x8 a[2], bfr[2];
    #pragma unroll
    for (int c = 0; c < 2; ++c)
      a[c] = *(const f16x8*)(repL + (size_t)(kt * 8 + 2 * w + c) * 512 + (size_t)lane * 8);
    #pragma unroll
    for (int p = 0; p < 2; ++p)
      bfr[p] = *(const f16x8*)((const char*)act + act_off(p * 32 + l31, (kt * 16 + ln5 * 8) * 2));
    #pragma unroll
    for (int c = 0; c < 2; ++c)
      #pragma unroll
      for (int p = 0; p < 2; ++p)
        acc[c][p] = __builtin_amdgcn_mfma_f32_32x32x16_f16(a[c], bfr[p], acc[c][p], 0, 0, 0);
  }

  __syncthreads();  // all B reads done -> safe to overwrite act in place

  // Epilogue: C row = (r&3) + 8*(r>>2) + 4*(l>>5), col = l&31 (pt).
  #pragma unroll
  for (int c = 0; c < 2; ++c) {
    #pragma unroll
    for (int p = 0; p < 2; ++p) {
      int pt = p * 32 + l31;
      #pragma unroll
      for (int g = 0; g < 4; ++g) {
        f16x4 h;
        #pragma unroll
        for (int q = 0; q < 4; ++q) {
          float v = acc[c][p][g * 4 + q];
          if (relu) v = fmaxf(v, 0.f);
          h[q] = (f16)v;
        }
        int ch = chb + c * 32 + g * 8 + (ln5 << 2);
        *(f16x4*)((char*)act + act_off(pt, ch * 2)) = h;
      }
    }
  }
}

// Views layer: in = feature(256 from act) + views(27 via reg frags), out = 128 ch.
// Wave w -> ch [32w, 32w+32).
__device__ __forceinline__ void layer_views64(
    const f16* repL, const float* bias, f16* act,
    const f16x8* vb, int lane, int w)
{
  const int l31 = lane & 31;
  const int ln5 = lane >> 5;
  const int chb = w * 32;

  f32x16 acc[2];
  #pragma unroll
  for (int g = 0; g < 4; ++g) {
    f32x4 bv = *(const f32x4*)(bias + chb + g * 8 + (ln5 << 2));
    #pragma unroll
    for (int q = 0; q < 4; ++q) {
      acc[0][g * 4 + q] = bv[q];
      acc[1][g * 4 + q] = bv[q];
    }
  }

  // Views part first (kills vb registers early).
  #pragma unroll
  for (int j = 0; j < 2; ++j) {
    int kt = 16 + j;
    f16x8 a = *(const f16x8*)(repL + (size_t)(kt * 4 + w) * 512 + (size_t)lane * 8);
    #pragma unroll
    for (int p = 0; p < 2; ++p)
      acc[p] = __builtin_amdgcn_mfma_f32_32x32x16_f16(a, vb[p * 2 + j], acc[p], 0, 0, 0);
  }

  __syncthreads();

  #pragma unroll 2
  for (int kt = 0; kt < 16; ++kt) {
    f16x8 a = *(const f16x8*)(repL + (size_t)(kt * 4 + w) * 512 + (size_t)lane * 8);
    f16x8 bfr[2];
    #pragma unroll
    for (int p = 0; p < 2; ++p)
      bfr[p] = *(const f16x8*)((const char*)act + act_off(p * 32 + l31, (kt * 16 + ln5 * 8) * 2));
    #pragma unroll
    for (int p = 0; p < 2; ++p)
      acc[p] = __builtin_amdgcn_mfma_f32_32x32x16_f16(a, bfr[p], acc[p], 0, 0, 0);
  }

  __syncthreads();

  #pragma unroll
  for (int p = 0; p < 2; ++p) {
    int pt = p * 32 + l31;
    #pragma unroll
    for (int g = 0; g < 4; ++g) {
      f16x4 h;
      #pragma unroll
      for (int q = 0; q < 4; ++q) {
        float v = fmaxf(acc[p][g * 4 + q], 0.f);
        h[q] = (f16)v;
      }
      int ch = chb + g * 8 + (ln5 << 2);
      *(f16x4*)((char*)act + act_off(pt, ch * 2)) = h;
    }
  }
}

// alpha = y . alpha_w + alpha_b. Thread t: pt = t&63, wave w sums ch [64w,64w+64).
__device__ __forceinline__ void alpha_pass(const f16* act, const float* aw,
                                           const float* ab, float* part,
                                           float* alds, int lane, int w)
{
  __syncthreads();
  int pt = lane;
  float s = 0.f;
  #pragma unroll
  for (int i = 0; i < 8; ++i) {
    int k0 = w * 64 + i * 8;
    f16x8 v = *(const f16x8*)((const char*)act + act_off(pt, k0 * 2));
    f32x4 wa = *(const f32x4*)(aw + k0);
    f32x4 wb = *(const f32x4*)(aw + k0 + 4);
    #pragma unroll
    for (int q = 0; q < 4; ++q) {
      s += (float)v[q] * wa[q];
      s += (float)v[q + 4] * wb[q];
    }
  }
  part[w * 64 + pt] = s;
  __syncthreads();
  if (w == 0)
    alds[pt] = part[pt] + part[64 + pt] + part[128 + pt] + part[192 + pt] + ab[0];
}

// rgb (128 -> 3 via one padded 32-ch MFMA tile) + packed store. Waves 0,1 only.
__device__ __forceinline__ void layer_rgb_store(
    const f16* repL, f16* act, const float* alds,
    const float* rgb_b, float* out, int pt0, int lane, int w)
{
  __syncthreads();
  if (w < 2) {
    f32x16 acc = {};
    #pragma unroll
    for (int kt = 0; kt < 8; ++kt) {
      f16x8 a = *(const f16x8*)(repL + (size_t)kt * 512 + (size_t)lane * 8);
      f16x8 b = *(const f16x8*)((const char*)act + act_off(w * 32 + (lane & 31), (kt * 16 + (lane >> 5) * 8) * 2));
      acc = __builtin_amdgcn_mfma_f32_32x32x16_f16(a, b, acc, 0, 0, 0);
    }
    if (lane < 32) {
      int pt = w * 32 + lane;
      float4 o;
      o.x = acc[0] + rgb_b[0];
      o.y = acc[1] + rgb_b[1];
      o.z = acc[2] + rgb_b[2];
      o.w = alds[pt];
      *(float4*)(out + (size_t)(pt0 + pt) * 4) = o;
    }
  }
}

__device__ __forceinline__ void load_pos_frags(const float* x, int pt0,
                                               int lane, f16x8* pf)
{
  const int l31 = lane & 31, ln5 = lane >> 5;
  #pragma unroll
  for (int p = 0; p < 2; ++p) {
    const float* row = x + (size_t)(pt0 + p * 32 + l31) * 90;
    #pragma unroll
    for (int kt = 0; kt < 4; ++kt) {
      f16x8 v;
      #pragma unroll
      for (int j = 0; j < 8; ++j) {
        int c = kt * 16 + ln5 * 8 + j;
        v[j] = (f16)((c < 63) ? row[c] : 0.f);
      }
      pf[p * 4 + kt] = v;
    }
  }
}

__device__ __forceinline__ void load_views_frags(const float* x, int pt0,
                                                 int lane, f16x8* vf)
{
  const int l31 = lane & 31, ln5 = lane >> 5;
  #pragma unroll
  for (int p = 0; p < 2; ++p) {
    const float* row = x + (size_t)(pt0 + p * 32 + l31) * 90;
    #pragma unroll
    for (int kt = 0; kt < 2; ++kt) {
      f16x8 v;
      #pragma unroll
      for (int j = 0; j < 8; ++j) {
        int c = kt * 16 + ln5 * 8 + j;
        v[j] = (f16)((c < 27) ? row[63 + c] : 0.f);
      }
      vf[p * 2 + kt] = v;
    }
  }
}

__global__ __launch_bounds__(256, 4) void nerf_main(MainParams P) {
  __shared__ __align__(16) f16 act[16384];   // 32 KB: [64 pt][256 k], swizzled
  __shared__ float part[256];
  __shared__ float alds[64];

  const int tid = threadIdx.x;
  const int lane = tid & 63;
  const int w = tid >> 6;
  const int pt0 = blockIdx.x * 64;

  {
    f16x8 pf[8];
    load_pos_frags(P.x, pt0, lane, pf);
    layer_std64<0, 4>(P.rep + OFF_W0, P.b[0], true, act, pf, lane, w);
  }
  layer_std64<16, 0>(P.rep + OFF_W1, P.b[1], true, act, nullptr, lane, w);
  layer_std64<16, 0>(P.rep + OFF_W2, P.b[2], true, act, nullptr, lane, w);
  layer_std64<16, 0>(P.rep + OFF_W3, P.b[3], true, act, nullptr, lane, w);
  layer_std64<16, 0>(P.rep + OFF_W4, P.b[4], true, act, nullptr, lane, w);
  {
    f16x8 pf[8];
    load_pos_frags(P.x, pt0, lane, pf);
    layer_std64<16, 4>(P.rep + OFF_W5, P.b[5], true, act, pf, lane, w);
  }
  layer_std64<16, 0>(P.rep + OFF_W6, P.b[6], true, act, nullptr, lane, w);
  layer_std64<16, 0>(P.rep + OFF_W7, P.b[7], true, act, nullptr, lane, w);

  alpha_pass(act, P.alpha_w, P.alpha_b, part, alds, lane, w);

  layer_std64<16, 0>(P.rep + OFF_FEAT, P.feat_b, false, act, nullptr, lane, w);

  {
    f16x8 vf[4];
    load_views_frags(P.x, pt0, lane, vf);
    layer_views64(P.rep + OFF_VIEWS, P.views_b, act, vf, lane, w);
  }

  layer_rgb_store(P.rep + OFF_RGB, act, alds, P.rgb_b, P.out, pt0, lane, w);

  // Second tuple output: zeros (N, 3) -> 192 floats per 64-pt block
  float* out2 = P.out + (size_t)NPTS * 4;
  if (tid < 96) {
    *(float2*)(out2 + (size_t)blockIdx.x * 192 + (size_t)tid * 2) = make_float2(0.f, 0.f);
  }
}

extern "C" void kernel_launch(void* const* d_in, const int* in_sizes, int n_in,
                              void* d_out, int out_size, void* d_ws, size_t ws_size,
                              hipStream_t stream) {
  (void)in_sizes; (void)n_in; (void)out_size; (void)ws_size;

  RepParams rp;
  rp.seg[0]  = { (const float*)d_in[1],    0,  63, 256, 8,    0 }; // w0 (pad K 63->64)
  rp.seg[1]  = { (const float*)d_in[3],    0, 256, 256, 8,   32 }; // w1
  rp.seg[2]  = { (const float*)d_in[5],    0, 256, 256, 8,  160 }; // w2
  rp.seg[3]  = { (const float*)d_in[7],    0, 256, 256, 8,  288 }; // w3
  rp.seg[4]  = { (const float*)d_in[9],    0, 256, 256, 8,  416 }; // w4
  rp.seg[5]  = { (const float*)d_in[11],  63, 256, 256, 8,  544 }; // w5 y-part (rows 63..318)
  rp.seg[6]  = { (const float*)d_in[11],   0,  63, 256, 8,  672 }; // w5 pos-part (rows 0..62)
  rp.seg[7]  = { (const float*)d_in[13],   0, 256, 256, 8,  704 }; // w6
  rp.seg[8]  = { (const float*)d_in[15],   0, 256, 256, 8,  832 }; // w7
  rp.seg[9]  = { (const float*)d_in[17],   0, 256, 256, 8,  960 }; // feat_w
  rp.seg[10] = { (const float*)d_in[21],   0, 256, 128, 4, 1088 }; // views_w feature-part
  rp.seg[11] = { (const float*)d_in[21], 256,  27, 128, 4, 1152 }; // views_w views-part
  rp.seg[12] = { (const float*)d_in[23],   0, 128,   3, 1, 1160 }; // rgb_w (pad 3->32 ch)
  rp.rep = (f16*)d_ws;
  repack_kernel<<<1168, 64, 0, stream>>>(rp);

  MainParams mp;
  mp.x = (const float*)d_in[0];
  for (int i = 0; i < 8; ++i) mp.b[i] = (const float*)d_in[2 + 2 * i];
  mp.feat_b  = (const float*)d_in[18];
  mp.alpha_w = (const float*)d_in[19];
  mp.alpha_b = (const float*)d_in[20];
  mp.views_b = (const float*)d_in[22];
  mp.rgb_b   = (const float*)d_in[24];
  mp.rep = (const f16*)d_ws;
  mp.out = (float*)d_out;
  nerf_main<<<4096, 256, 0, stream>>>(mp);
}